// Round 5
// baseline (1087.340 us; speedup 1.0000x reference)
//
#include <hip/hip_runtime.h>
#include <hip/hip_bf16.h>
#include <hip/hip_fp16.h>

// ---------------------------------------------------------------------------
// Attention (B=4, S=4096, d_model=d_attn=2048), fp32 in/out, bf16 MFMA.
// R4: free-running GEMM inner loop (AITER s02 pattern): BK=32, 4-parity LDS
//     (128 KiB), depth-3 staging, ONE raw s_barrier + counted vmcnt(4) per
//     K-tile (32 MFMA/wave/barrier), cross-tile B-register-prefetch, NO
//     manual lgkmcnt (compiler scoreboard emits counted waits). Same st_16x32
//     swizzle + verified 16x16x32 layouts + outer pipeline as R3.
// Invariants (per-wave FIFO): body(t) issues 4 loads (t+3); at body(t) end
//     outstanding = {t+2:4, t+3:4} -> vmcnt(4) retires t+2. Reads of tile t+1
//     issued during t are safe: t+1 retired at body(t-1)'s vmcnt. DMA at t
//     targets parity (t+3)&3=(t-1)&3 whose readers finished before the
//     t-1 -> t boundary barrier (their lgkm waits precede barrier arrival).
// Workspace: 416 MiB batched path (per-batch fallback at 320 MiB).
// ---------------------------------------------------------------------------

#define S_ 4096
#define DM_ 2048
#define DA_ 2048
#define NB_ 4

typedef __attribute__((ext_vector_type(8))) short short8;
typedef __attribute__((ext_vector_type(4))) float f32x4;
typedef __attribute__((ext_vector_type(8))) unsigned short ushort8;

__device__ __forceinline__ void gload_lds16(const void* g, void* l) {
  __builtin_amdgcn_global_load_lds(
      (const __attribute__((address_space(1))) void*)g,
      (__attribute__((address_space(3))) void*)l, 16, 0, 0);
}

__device__ __forceinline__ unsigned short f2bf(float f) {
  __hip_bfloat16 h = __float2bfloat16(f);
  return __builtin_bit_cast(unsigned short, h);
}

// stage one K32 tile half (A: rows, 2 gloads; B: rows, 2 gloads)
#define STG_A(par, kt)                                                  \
  {                                                                     \
    const __hip_bfloat16* s_ = Asrc + (size_t)(kt)*32;                  \
    gload_lds16(s_, ldsw + (par)*32768 + dA);                           \
    gload_lds16(s_ + (size_t)128 * lda, ldsw + (par)*32768 + 8192 + dA);\
  }
#define STG_B(par, kt)                                                  \
  {                                                                     \
    const __hip_bfloat16* s_ = Bsrc + (size_t)(kt)*32;                  \
    gload_lds16(s_, ldsw + (par)*32768 + 16384 + dA);                   \
    gload_lds16(s_ + (size_t)128 * ldb, ldsw + (par)*32768 + 24576 + dA);\
  }
#define LDA8(par, a) (*(const short8*)(ldsA + (par)*32768 + (a)*1024))
#define LDB4(par, j) (*(const short8*)(ldsB + (par)*32768 + (j)*1024))

// one K32 tile: 8 A-frag reads, stage t+3, 32 MFMA, prefetch next-tile B,
// counted vmcnt(4), single raw barrier.
#define TILE(PAR, BU, BV, t)                                                 \
  {                                                                          \
    short8 A8[8];                                                            \
    _Pragma("unroll") for (int a = 0; a < 8; ++a) A8[a] = LDA8(PAR, a);      \
    {                                                                        \
      const int tf = min((t) + 3, NT - 1);                                   \
      STG_A(((PAR) + 3) & 3, tf);                                            \
      STG_B(((PAR) + 3) & 3, tf);                                            \
    }                                                                        \
    _Pragma("unroll") for (int a = 0; a < 8; ++a)                            \
        _Pragma("unroll") for (int j = 0; j < 4; ++j)                        \
            acc[a][j] = __builtin_amdgcn_mfma_f32_16x16x32_bf16(             \
                A8[a], BU[j], acc[a][j], 0, 0, 0);                           \
    _Pragma("unroll") for (int j = 0; j < 4; ++j)                            \
        BV[j] = LDB4(((PAR) + 1) & 3, j);                                    \
    asm volatile("s_waitcnt vmcnt(4)" ::: "memory");                         \
    __builtin_amdgcn_s_barrier();                                            \
  }

// C[M,N] = A[M,K] * B[N,K]^T ; 256x256 tile, 8 waves, BK=32, 4-parity LDS.
// EPI 0: C bf16 ; EPI 1: C fp16 * scale ; EPI 2: C fp32 + bias[col]
template <int EPI>
__device__ __forceinline__ void gemm8_body(
    const __hip_bfloat16* __restrict__ A, const __hip_bfloat16* __restrict__ Bm,
    void* __restrict__ Cv, const float* __restrict__ bias, int N, int K,
    int lda, int ldb, int ldc, float scale, long strideA, long strideB,
    long strideC) {
  __shared__ alignas(16) char lds[131072];
  char* ldsw = lds;
  const int tid = threadIdx.x;
  const int lane = tid & 63;
  const int w = tid >> 6;
  const int wr = w >> 2, wc = w & 3;

  // bijective XCD swizzle (all grids divisible by 8)
  const int nwg = (int)gridDim.x;
  int wg = (int)blockIdx.x;
  wg = (wg & 7) * (nwg >> 3) + (wg >> 3);
  const int nbn = N >> 8;
  const int bm = wg / nbn, bn = wg % nbn;

  A += (long)blockIdx.y * strideA;
  Bm += (long)blockIdx.y * strideB;

  // staging source coords (pre-swizzled column: involution of read XOR)
  const int Rr = tid >> 2;                                  // 0..127
  const int Cc = ((tid & 3) << 3) ^ ((lane & 32) >> 1);     // elems 0..31
  const __hip_bfloat16* Asrc = A + (size_t)(bm * 256 + Rr) * lda + Cc;
  const __hip_bfloat16* Bsrc = Bm + (size_t)(bn * 256 + Rr) * ldb + Cc;
  const int dA = w * 1024 + lane * 16;  // linear LDS dest within region

  // read-side swizzled bases (st_16x32: byte5 ^= row-bit3)
  const int fr = lane & 15;
  const int rby = fr * 64 + ((((lane >> 4) << 4)) ^ ((fr & 8) << 2));
  const char* ldsA = lds + wr * 8192 + rby;
  const char* ldsB = lds + 16384 + wc * 4096 + rby;

  const int NT = K >> 5;  // K32 tiles; all K here are multiples of 128
  f32x4 acc[8][4] = {};

  // prologue: stage tiles 0,1,2 (12 loads); vmcnt(4) retires t0,t1 (leaves
  // t2 in flight = steady state); then prefetch B(0) into registers.
  STG_A(0, 0) STG_B(0, 0)
  STG_A(1, 1) STG_B(1, 1)
  STG_A(2, 2) STG_B(2, 2)
  asm volatile("s_waitcnt vmcnt(4)" ::: "memory");
  __builtin_amdgcn_s_barrier();

  short8 Bu[4], Bv[4];
#pragma unroll
  for (int j = 0; j < 4; ++j) Bu[j] = LDB4(0, j);

  for (int t = 0; t < NT; t += 4) {
    TILE(0, Bu, Bv, t)
    TILE(1, Bv, Bu, t + 1)
    TILE(2, Bu, Bv, t + 2)
    TILE(3, Bv, Bu, t + 3)
  }
  asm volatile("s_waitcnt vmcnt(0)" ::: "memory");

  // epilogue: C/D layout col=lane&15, row=(lane>>4)*4+reg  [verified m89/m91]
  float* Cf = (float*)Cv;
  __hip_bfloat16* Cb = (__hip_bfloat16*)Cv;
  __half* Ch = (__half*)Cv;
  const size_t cbase = (size_t)blockIdx.y * (size_t)strideC;
  const int r0 = bm * 256 + wr * 128 + ((lane >> 4) << 2);
  const int c0 = bn * 256 + wc * 64 + fr;
#pragma unroll
  for (int a = 0; a < 8; ++a)
#pragma unroll
    for (int j = 0; j < 4; ++j) {
      const int row = r0 + a * 16;
      const int col = c0 + j * 16;
#pragma unroll
      for (int r = 0; r < 4; ++r) {
        const float v = acc[a][j][r];
        if (EPI == 0)
          Cb[cbase + (size_t)(row + r) * ldc + col] = __float2bfloat16(v);
        else if (EPI == 1)
          Ch[cbase + (size_t)(row + r) * ldc + col] = __float2half(v * scale);
        else
          Cf[cbase + (size_t)(row + r) * ldc + col] = v + bias[col];
      }
    }
}

#define GEMM_WRAP(NAME, EPI)                                                   \
  __global__ __launch_bounds__(512, 2) void NAME(                             \
      const __hip_bfloat16* __restrict__ A,                                   \
      const __hip_bfloat16* __restrict__ Bm, void* __restrict__ Cv,           \
      const float* __restrict__ bias, int N, int K, int lda, int ldb,         \
      int ldc, float scale, long strideA, long strideB, long strideC) {       \
    gemm8_body<EPI>(A, Bm, Cv, bias, N, K, lda, ldb, ldc, scale, strideA,     \
                    strideB, strideC);                                        \
  }
GEMM_WRAP(g_qkproj, 0)
GEMM_WRAP(g_vt, 0)
GEMM_WRAP(g_qkt, 1)
GEMM_WRAP(g_pv, 0)
GEMM_WRAP(g_out, 2)

// one block per 4096-wide row: read fp16 logits, write bf16 probs IN PLACE
__global__ __launch_bounds__(256) void softmax_inplace(void* __restrict__ buf) {
  const int t = threadIdx.x;
  unsigned short* rp = (unsigned short*)buf + (size_t)blockIdx.x * S_;
  ushort8 h0 = ((const ushort8*)rp)[t * 2];
  ushort8 h1 = ((const ushort8*)rp)[t * 2 + 1];
  float v[16];
#pragma unroll
  for (int j = 0; j < 8; ++j) {
    v[j] = __half2float(__builtin_bit_cast(__half, (unsigned short)h0[j]));
    v[8 + j] = __half2float(__builtin_bit_cast(__half, (unsigned short)h1[j]));
  }
  float m = -1e30f;
#pragma unroll
  for (int j = 0; j < 16; ++j) m = fmaxf(m, v[j]);
#pragma unroll
  for (int off = 32; off > 0; off >>= 1) m = fmaxf(m, __shfl_xor(m, off));
  __shared__ float red[8];
  const int wv = t >> 6;
  if ((t & 63) == 0) red[wv] = m;
  __syncthreads();
  m = fmaxf(fmaxf(red[0], red[1]), fmaxf(red[2], red[3]));
  float e[16], s = 0.f;
#pragma unroll
  for (int j = 0; j < 16; ++j) {
    e[j] = __expf(v[j] - m);
    s += e[j];
  }
#pragma unroll
  for (int off = 32; off > 0; off >>= 1) s += __shfl_xor(s, off);
  if ((t & 63) == 0) red[4 + wv] = s;
  __syncthreads();
  s = (red[4] + red[5]) + (red[6] + red[7]);
  const float inv = 1.0f / s;
  ushort8 o0, o1;
#pragma unroll
  for (int j = 0; j < 8; ++j) {
    o0[j] = f2bf(e[j] * inv);
    o1[j] = f2bf(e[8 + j] * inv);
  }
  ((ushort8*)rp)[t * 2] = o0;
  ((ushort8*)rp)[t * 2 + 1] = o1;
}

// fused cast: x (16384 blocks) + Wq,Wk,Wv,Wo (2048 blocks each), 8 elems/thr
__global__ __launch_bounds__(256) void cast_all(
    const float* __restrict__ x, const float* __restrict__ wq,
    const float* __restrict__ wk, const float* __restrict__ wv,
    const float* __restrict__ wo, __hip_bfloat16* __restrict__ xb,
    __hip_bfloat16* __restrict__ wqkb, __hip_bfloat16* __restrict__ wvb,
    __hip_bfloat16* __restrict__ wob) {
  const int b = blockIdx.x;
  const float* src;
  __hip_bfloat16* dst;
  long base;
  if (b < 16384) {
    src = x; dst = xb; base = (long)b;
  } else if (b < 18432) {
    src = wq; dst = wqkb; base = (long)(b - 16384);
  } else if (b < 20480) {
    src = wk; dst = wqkb + (long)DA_ * DM_; base = (long)(b - 18432);
  } else if (b < 22528) {
    src = wv; dst = wvb; base = (long)(b - 20480);
  } else {
    src = wo; dst = wob; base = (long)(b - 22528);
  }
  const long i = (base * 256 + threadIdx.x) * 8;
  const f32x4 a = *(const f32x4*)(src + i);
  const f32x4 c = *(const f32x4*)(src + i + 4);
  ushort8 o;
#pragma unroll
  for (int j = 0; j < 4; ++j) o[j] = f2bf(a[j]);
#pragma unroll
  for (int j = 0; j < 4; ++j) o[4 + j] = f2bf(c[j]);
  *(ushort8*)(dst + i) = o;
}

extern "C" void kernel_launch(void* const* d_in, const int* in_sizes, int n_in,
                              void* d_out, int out_size, void* d_ws,
                              size_t ws_size, hipStream_t stream) {
  (void)in_sizes; (void)n_in; (void)out_size;
  const float* x = (const float*)d_in[0];
  const float* Wq = (const float*)d_in[1];
  const float* Wk = (const float*)d_in[2];
  const float* Wv = (const float*)d_in[3];
  const float* Wo = (const float*)d_in[4];
  const float* bo = (const float*)d_in[5];
  float* out = (float*)d_out;

  const long MB = 1ll << 20;
  char* ws = (char*)d_ws;
  __hip_bfloat16* Xb   = (__hip_bfloat16*)(ws);             // 64 MiB
  __hip_bfloat16* QKb  = (__hip_bfloat16*)(ws + 64 * MB);   // 128 MiB (Q|K)
  __hip_bfloat16* Vt   = (__hip_bfloat16*)(ws + 192 * MB);  // 64 MiB
  __hip_bfloat16* Wqkb = (__hip_bfloat16*)(ws + 256 * MB);  // 16 MiB
  __hip_bfloat16* Wvb  = (__hip_bfloat16*)(ws + 272 * MB);  // 8 MiB
  __hip_bfloat16* Wob  = (__hip_bfloat16*)(ws + 280 * MB);  // 8 MiB
  char* LgP            = ws + 288 * MB;  // 128 MiB batched / 32 MiB per-batch
  __hip_bfloat16* AO = Xb;  // x dead after projections; reuse

  const bool batched = ws_size >= (size_t)(416 * MB);

  cast_all<<<dim3(24576), dim3(256), 0, stream>>>(x, Wq, Wk, Wv, Wo, Xb, Wqkb,
                                                  Wvb, Wob);

  // fused Q|K projection: [16384, 4096] = Xb @ [Wq;Wk]^T
  g_qkproj<<<dim3(1024, 1), dim3(512), 0, stream>>>(
      Xb, Wqkb, QKb, nullptr, 4096, 2048, 2048, 2048, 4096, 1.f, 0, 0, 0);
  // Vt (batched): [2048, 4096] = Wv @ Xb_b^T
  g_vt<<<dim3(128, NB_), dim3(512), 0, stream>>>(
      Wvb, Xb, Vt, nullptr, 4096, 2048, 2048, 2048, 4096, 1.f, 0,
      (long)S_ * DM_, (long)DA_ * S_);

  const float scale = 0.022097086912079608f;  // 1/sqrt(d_model=2048)
  if (batched) {
    g_qkt<<<dim3(256, NB_), dim3(512), 0, stream>>>(
        QKb, QKb + DA_, LgP, nullptr, 4096, 2048, 4096, 4096, 4096, scale,
        (long)S_ * 2 * DA_, (long)S_ * 2 * DA_, (long)S_ * S_);
    softmax_inplace<<<dim3(NB_ * S_), dim3(256), 0, stream>>>(LgP);
    g_pv<<<dim3(128, NB_), dim3(512), 0, stream>>>(
        (const __hip_bfloat16*)LgP, Vt, AO, nullptr, 2048, 4096, 4096, 4096,
        2048, 1.f, (long)S_ * S_, (long)DA_ * S_, (long)S_ * DA_);
  } else {
    for (int b = 0; b < NB_; ++b) {
      const __hip_bfloat16* Qb = QKb + (size_t)b * S_ * 2 * DA_;
      g_qkt<<<dim3(256, 1), dim3(512), 0, stream>>>(
          Qb, Qb + DA_, LgP, nullptr, 4096, 2048, 4096, 4096, 4096, scale, 0,
          0, 0);
      softmax_inplace<<<dim3(S_), dim3(256), 0, stream>>>(LgP);
      g_pv<<<dim3(128, 1), dim3(512), 0, stream>>>(
          (const __hip_bfloat16*)LgP, Vt + (size_t)b * DA_ * S_,
          AO + (size_t)b * S_ * DA_, nullptr, 2048, 4096, 4096, 4096, 2048,
          1.f, 0, 0, 0);
    }
  }
  // out = AO @ Wo^T + bo (fp32)
  g_out<<<dim3(512, 1), dim3(512), 0, stream>>>(
      AO, Wob, out, bo, 2048, 2048, 2048, 2048, 2048, 1.f, 0, 0, 0);
}